// Round 3
// baseline (1082.858 us; speedup 1.0000x reference)
//
#include <hip/hip_runtime.h>
#include <math.h>

#define F0 512
#define F1 16
#define F2 40
#define RPB 32          // rows per bucket
#define RPB_SHIFT 5
#define COL_BITS 17     // n <= 131072

__global__ void k_zero(int* p, int m) {
    int i = blockIdx.x * blockDim.x + threadIdx.x;
    if (i < m) p[i] = 0;
}

// ---------------- pass A: bucket histogram ----------------
__global__ __launch_bounds__(256) void k_bhist(const int* __restrict__ row, int E,
                                               int* __restrict__ bhist) {
    int base = (blockIdx.x * blockDim.x + threadIdx.x) * 4;
    if (base + 3 < E) {
        int4 r = *(const int4*)(row + base);
        atomicAdd(&bhist[r.x >> RPB_SHIFT], 1);
        atomicAdd(&bhist[r.y >> RPB_SHIFT], 1);
        atomicAdd(&bhist[r.z >> RPB_SHIFT], 1);
        atomicAdd(&bhist[r.w >> RPB_SHIFT], 1);
    } else {
        for (int e = base; e < E; e++) atomicAdd(&bhist[row[e] >> RPB_SHIFT], 1);
    }
}

// ---------------- pass B: single-block exclusive scan of NB buckets ----------------
__global__ __launch_bounds__(1024) void k_bscan(const int* __restrict__ bhist, int NB,
                                                int* __restrict__ bstart,
                                                int* __restrict__ bcursor) {
    __shared__ int part[1024];
    int t = threadIdx.x;
    int v[4], s = 0;
#pragma unroll
    for (int q = 0; q < 4; q++) {
        int idx = t * 4 + q;
        v[q] = (idx < NB) ? bhist[idx] : 0;
        s += v[q];
    }
    part[t] = s;
    __syncthreads();
    for (int off = 1; off < 1024; off <<= 1) {
        int a = (t >= off) ? part[t - off] : 0;
        __syncthreads();
        part[t] += a;
        __syncthreads();
    }
    int run = (t > 0) ? part[t - 1] : 0;
#pragma unroll
    for (int q = 0; q < 4; q++) {
        int idx = t * 4 + q;
        if (idx < NB) { bstart[idx] = run; bcursor[idx] = run; }
        run += v[q];
    }
}

// ---------------- pass C: scatter packed edges to bucket tails ----------------
__global__ __launch_bounds__(256) void k_bfill(const int* __restrict__ row,
                                               const int* __restrict__ col, int E,
                                               int* bcursor, int* __restrict__ ebuf) {
    int base = (blockIdx.x * blockDim.x + threadIdx.x) * 4;
#pragma unroll
    for (int q = 0; q < 4; q++) {
        int e = base + q;
        if (e < E) {
            int r = row[e], c = col[e];
            int p = atomicAdd(&bcursor[r >> RPB_SHIFT], 1);
            ebuf[p] = ((r & (RPB - 1)) << COL_BITS) | c;
        }
    }
}

// ---------------- pass D: per-bucket counting sort -> colsort, deg, rs, dinv ----
__global__ __launch_bounds__(256) void k_bsort(const int* __restrict__ ebuf,
                                               const int* __restrict__ bstart, int NB,
                                               int E, int n, int* __restrict__ colsort,
                                               int* __restrict__ deg,
                                               int* __restrict__ rs,
                                               float* __restrict__ dinv) {
    __shared__ int cnt[RPB];
    __shared__ int sexcl[RPB];
    int b = blockIdx.x;
    int t = threadIdx.x;
    int r0 = b << RPB_SHIFT;
    int start = bstart[b];
    int end = (b + 1 < NB) ? bstart[b + 1] : E;
    if (t < RPB) cnt[t] = 0;
    __syncthreads();
    for (int e = start + t; e < end; e += 256)
        atomicAdd(&cnt[ebuf[e] >> COL_BITS], 1);
    __syncthreads();
    if (t == 0) {
        int run = 0;
        for (int j = 0; j < RPB; j++) { sexcl[j] = run; run += cnt[j]; }
    }
    __syncthreads();
    if (t < RPB) {
        int i = r0 + t;
        if (i < n) {
            deg[i] = cnt[t];
            rs[i] = start + sexcl[t];
            dinv[i] = rsqrtf((float)(cnt[t] + 1));
        }
        cnt[t] = sexcl[t];  // reuse as cursor
    }
    __syncthreads();
    for (int e = start + t; e < end; e += 256) {
        int v = ebuf[e];
        int lr = v >> COL_BITS;
        int p = atomicAdd(&cnt[lr], 1);
        colsort[start + p] = v & ((1 << COL_BITS) - 1);
    }
}

// ---------------- GEMM1: hp[i][j] = dinv[i] * (x[i,:] @ W1[:,j]) ----------------
__global__ __launch_bounds__(256) void k_gemm1(const float* __restrict__ x,
                                               const float* __restrict__ W1,
                                               const float* __restrict__ dinv,
                                               float* __restrict__ hp, int n,
                                               int total_waves) {
    int lane = threadIdx.x & 63;
    int wid = blockIdx.x * (blockDim.x >> 6) + (threadIdx.x >> 6);

    float w[8][16];
#pragma unroll
    for (int h = 0; h < 2; h++) {
#pragma unroll
        for (int r = 0; r < 4; r++) {
            int k = h * 256 + 4 * lane + r;
            const float4* p = (const float4*)(W1 + k * 16);
            float4 a = p[0], b = p[1], c = p[2], d = p[3];
            float* wr = w[h * 4 + r];
            wr[0] = a.x; wr[1] = a.y; wr[2] = a.z; wr[3] = a.w;
            wr[4] = b.x; wr[5] = b.y; wr[6] = b.z; wr[7] = b.w;
            wr[8] = c.x; wr[9] = c.y; wr[10] = c.z; wr[11] = c.w;
            wr[12] = d.x; wr[13] = d.y; wr[14] = d.z; wr[15] = d.w;
        }
    }

    for (int i = wid; i < n; i += total_waves) {
        const float4* xp = (const float4*)(x + (size_t)i * F0);
        float4 xa = xp[lane];
        float4 xb = xp[64 + lane];
        float acc[16];
#pragma unroll
        for (int j = 0; j < 16; j++) {
            acc[j] = xa.x * w[0][j] + xa.y * w[1][j] + xa.z * w[2][j] + xa.w * w[3][j]
                   + xb.x * w[4][j] + xb.y * w[5][j] + xb.z * w[6][j] + xb.w * w[7][j];
        }
#pragma unroll
        for (int j = 0; j < 16; j++) {
            float v = acc[j];
            v += __shfl_xor(v, 1);
            v += __shfl_xor(v, 2);
            v += __shfl_xor(v, 4);
            v += __shfl_xor(v, 8);
            v += __shfl_xor(v, 16);
            v += __shfl_xor(v, 32);
            acc[j] = v;
        }
        if (lane < 16) {
            float v = acc[0];
#pragma unroll
            for (int j = 1; j < 16; j++) v = (lane == j) ? acc[j] : v;
            hp[(size_t)i * F1 + lane] = dinv[i] * v;
        }
    }
}

// ---------------- SpMM1 + relu, store s2 = dinv * h1 (16 feats) ----------------
__global__ __launch_bounds__(256) void k_spmm1(const float* __restrict__ hp,
                                               const int* __restrict__ rs,
                                               const int* __restrict__ deg,
                                               const int* __restrict__ colsort,
                                               const float* __restrict__ dinv,
                                               const float* __restrict__ b1,
                                               float* __restrict__ s2, int n) {
    int t = threadIdx.x;
    int lane = t & 63;
    int g = lane >> 4;
    int jf = lane & 15;
    int i = blockIdx.x * 4 + (t >> 6);
    if (i >= n) return;
    int s = rs[i], c = deg[i];
    float acc = (g == 0) ? hp[(size_t)i * F1 + jf] : 0.f;
    int e = g;
    for (; e + 4 < c; e += 8) {
        int c0 = colsort[s + e];
        int c1 = colsort[s + e + 4];
        float v0 = hp[(size_t)c0 * F1 + jf];
        float v1 = hp[(size_t)c1 * F1 + jf];
        acc += v0 + v1;
    }
    if (e < c) acc += hp[(size_t)colsort[s + e] * F1 + jf];
    acc += __shfl_xor(acc, 16);
    acc += __shfl_xor(acc, 32);
    float di = dinv[i];
    float h1 = fmaxf(di * acc + b1[jf], 0.f);
    if (lane < 16) s2[(size_t)i * F1 + jf] = di * h1;
}

// ---------------- SpMM2 (16 feats) + GEMM2 + bias + log_softmax ----------------
__global__ __launch_bounds__(256) void k_spmm2(const float* __restrict__ s2,
                                               const int* __restrict__ rs,
                                               const int* __restrict__ deg,
                                               const int* __restrict__ colsort,
                                               const float* __restrict__ dinv,
                                               const float* __restrict__ W2,
                                               const float* __restrict__ b2,
                                               float* __restrict__ out, int n) {
    __shared__ float sW2[F1 * F2];
    int t = threadIdx.x;
    for (int idx = t; idx < F1 * F2; idx += 256) sW2[idx] = W2[idx];
    __syncthreads();

    int lane = t & 63;
    int g = lane >> 4;
    int jf = lane & 15;
    int i = blockIdx.x * 4 + (t >> 6);
    if (i >= n) return;
    int s = rs[i], c = deg[i];
    float acc = (g == 0) ? s2[(size_t)i * F1 + jf] : 0.f;
    int e = g;
    for (; e + 4 < c; e += 8) {
        int c0 = colsort[s + e];
        int c1 = colsort[s + e + 4];
        float v0 = s2[(size_t)c0 * F1 + jf];
        float v1 = s2[(size_t)c1 * F1 + jf];
        acc += v0 + v1;
    }
    if (e < c) acc += s2[(size_t)colsort[s + e] * F1 + jf];
    acc += __shfl_xor(acc, 16);
    acc += __shfl_xor(acc, 32);
    float z = dinv[i] * acc;

    bool act = lane < F2;
    int k = act ? lane : 0;
    float o = 0.f;
#pragma unroll
    for (int j = 0; j < F1; j++) {
        float zj = __shfl(z, j);
        o += zj * sW2[j * F2 + k];
    }
    float val = act ? o + b2[k] : -INFINITY;
    float m = val;
#pragma unroll
    for (int off = 1; off < 64; off <<= 1) m = fmaxf(m, __shfl_xor(m, off));
    float ex = act ? __expf(val - m) : 0.f;
    float ssum = ex;
#pragma unroll
    for (int off = 1; off < 64; off <<= 1) ssum += __shfl_xor(ssum, off);
    if (act) out[(size_t)i * F2 + lane] = val - m - __logf(ssum);
}

extern "C" void kernel_launch(void* const* d_in, const int* in_sizes, int n_in,
                              void* d_out, int out_size, void* d_ws, size_t ws_size,
                              hipStream_t stream) {
    const float* x  = (const float*)d_in[0];
    const float* W1 = (const float*)d_in[1];
    const float* b1 = (const float*)d_in[2];
    const float* W2 = (const float*)d_in[3];
    const float* b2 = (const float*)d_in[4];
    const int*   ei = (const int*)d_in[5];

    int n = in_sizes[0] / F0;
    int E = in_sizes[5] / 2;
    const int* row = ei;
    const int* col = ei + E;
    int NB = (n + RPB - 1) >> RPB_SHIFT;

    // workspace carve-up (4-byte elements)
    int* deg     = (int*)d_ws;          // n
    int* rs      = deg + n;             // n
    float* dinv  = (float*)(rs + n);    // n
    int* bhist   = (int*)(dinv + n);    // NB
    int* bstart  = bhist + NB;          // NB
    int* bcursor = bstart + NB;         // NB
    int* colsort = bcursor + NB;        // E
    int* ebuf    = colsort + E;         // max(E, 32n) — overlaid with hp/s2 below
    float* hp    = (float*)ebuf;        // n x 16 (ebuf dead after k_bsort)
    float* s2    = hp + (size_t)n * F1; // n x 16

    k_zero<<<(NB + 255) / 256, 256, 0, stream>>>(bhist, NB);
    k_bhist<<<(E + 1023) / 1024, 256, 0, stream>>>(row, E, bhist);
    k_bscan<<<1, 1024, 0, stream>>>(bhist, NB, bstart, bcursor);
    k_bfill<<<(E + 1023) / 1024, 256, 0, stream>>>(row, col, E, bcursor, ebuf);
    k_bsort<<<NB, 256, 0, stream>>>(ebuf, bstart, NB, E, n, colsort, deg, rs, dinv);

    int g1_blocks = 2048;
    k_gemm1<<<g1_blocks, 256, 0, stream>>>(x, W1, dinv, hp, n, g1_blocks * 4);
    k_spmm1<<<(n + 3) / 4, 256, 0, stream>>>(hp, rs, deg, colsort, dinv, b1, s2, n);
    k_spmm2<<<(n + 3) / 4, 256, 0, stream>>>(s2, rs, deg, colsort, dinv, W2, b2,
                                             (float*)d_out, n);
}

// Round 4
// 883.737 us; speedup vs baseline: 1.2253x; 1.2253x over previous
//
#include <hip/hip_runtime.h>
#include <math.h>

#define F0 512
#define F1 16
#define F2 40
#define RPB 32          // rows per bucket
#define RPB_SHIFT 5
#define COL_BITS 17     // n <= 131072
#define NG 8            // XCD groups
#define NG_SHIFT 3

__global__ void k_zero(int* p, int m) {
    int i = blockIdx.x * blockDim.x + threadIdx.x;
    if (i < m) p[i] = 0;
}

// ---------------- pass A: (bucket, xcd-group) histogram ----------------
__global__ __launch_bounds__(256) void k_bhist(const int* __restrict__ row, int E,
                                               int* __restrict__ bhist) {
    int g = blockIdx.x & (NG - 1);
    int base = (blockIdx.x * blockDim.x + threadIdx.x) * 4;
    if (base + 3 < E) {
        int4 r = *(const int4*)(row + base);
        atomicAdd(&bhist[((r.x >> RPB_SHIFT) << NG_SHIFT) | g], 1);
        atomicAdd(&bhist[((r.y >> RPB_SHIFT) << NG_SHIFT) | g], 1);
        atomicAdd(&bhist[((r.z >> RPB_SHIFT) << NG_SHIFT) | g], 1);
        atomicAdd(&bhist[((r.w >> RPB_SHIFT) << NG_SHIFT) | g], 1);
    } else {
        for (int e = base; e < E; e++)
            atomicAdd(&bhist[((row[e] >> RPB_SHIFT) << NG_SHIFT) | g], 1);
    }
}

// ---------------- pass B: exclusive scan of NB*NG counters ----------------
// order (bucket, group) -> each bucket's region stays contiguous; also emits
// per-bucket starts for k_bsort.
__global__ __launch_bounds__(1024) void k_bscan(const int* __restrict__ bhist, int NEL,
                                                int* __restrict__ bcursor,
                                                int* __restrict__ bstart) {
    __shared__ int part[1024];
    int t = threadIdx.x;
    int Q = (NEL + 1023) / 1024;
    int i0 = t * Q;
    int s = 0;
    for (int q = 0; q < Q; q++) {
        int idx = i0 + q;
        if (idx < NEL) s += bhist[idx];
    }
    part[t] = s;
    __syncthreads();
    for (int off = 1; off < 1024; off <<= 1) {
        int a = (t >= off) ? part[t - off] : 0;
        __syncthreads();
        part[t] += a;
        __syncthreads();
    }
    int run = (t > 0) ? part[t - 1] : 0;
    for (int q = 0; q < Q; q++) {
        int idx = i0 + q;
        if (idx < NEL) {
            int v = bhist[idx];
            bcursor[idx] = run;
            if ((idx & (NG - 1)) == 0) bstart[idx >> NG_SHIFT] = run;
            run += v;
        }
    }
}

// ---------------- pass C: scatter packed edges to (bucket, group) tails ----------
// group = blockIdx & 7 matches the round-robin block->XCD mapping, so all writes
// to a given tail line come from one XCD's L2 -> full-line writebacks.
__global__ __launch_bounds__(256) void k_bfill(const int* __restrict__ row,
                                               const int* __restrict__ col, int E,
                                               int* bcursor, int* __restrict__ ebuf) {
    int g = blockIdx.x & (NG - 1);
    int base = (blockIdx.x * blockDim.x + threadIdx.x) * 4;
#pragma unroll
    for (int q = 0; q < 4; q++) {
        int e = base + q;
        if (e < E) {
            int r = row[e], c = col[e];
            int p = atomicAdd(&bcursor[((r >> RPB_SHIFT) << NG_SHIFT) | g], 1);
            ebuf[p] = ((r & (RPB - 1)) << COL_BITS) | c;
        }
    }
}

// ---------------- pass D: per-bucket counting sort -> colsort, deg, rs, dinv ----
__global__ __launch_bounds__(256) void k_bsort(const int* __restrict__ ebuf,
                                               const int* __restrict__ bstart, int NB,
                                               int E, int n, int* __restrict__ colsort,
                                               int* __restrict__ deg,
                                               int* __restrict__ rs,
                                               float* __restrict__ dinv) {
    __shared__ int cnt[RPB];
    __shared__ int sexcl[RPB];
    int b = blockIdx.x;
    int t = threadIdx.x;
    int r0 = b << RPB_SHIFT;
    int start = bstart[b];
    int end = (b + 1 < NB) ? bstart[b + 1] : E;
    if (t < RPB) cnt[t] = 0;
    __syncthreads();
    for (int e = start + t; e < end; e += 256)
        atomicAdd(&cnt[ebuf[e] >> COL_BITS], 1);
    __syncthreads();
    if (t == 0) {
        int run = 0;
        for (int j = 0; j < RPB; j++) { sexcl[j] = run; run += cnt[j]; }
    }
    __syncthreads();
    if (t < RPB) {
        int i = r0 + t;
        if (i < n) {
            deg[i] = cnt[t];
            rs[i] = start + sexcl[t];
            dinv[i] = rsqrtf((float)(cnt[t] + 1));
        }
        cnt[t] = sexcl[t];  // reuse as cursor
    }
    __syncthreads();
    for (int e = start + t; e < end; e += 256) {
        int v = ebuf[e];
        int lr = v >> COL_BITS;
        int p = atomicAdd(&cnt[lr], 1);
        colsort[start + p] = v & ((1 << COL_BITS) - 1);
    }
}

// ---------------- GEMM1: hp[i][j] = dinv[i] * (x[i,:] @ W1[:,j]) ----------------
__global__ __launch_bounds__(256) void k_gemm1(const float* __restrict__ x,
                                               const float* __restrict__ W1,
                                               const float* __restrict__ dinv,
                                               float* __restrict__ hp, int n,
                                               int total_waves) {
    int lane = threadIdx.x & 63;
    int wid = blockIdx.x * (blockDim.x >> 6) + (threadIdx.x >> 6);

    float w[8][16];
#pragma unroll
    for (int h = 0; h < 2; h++) {
#pragma unroll
        for (int r = 0; r < 4; r++) {
            int k = h * 256 + 4 * lane + r;
            const float4* p = (const float4*)(W1 + k * 16);
            float4 a = p[0], b = p[1], c = p[2], d = p[3];
            float* wr = w[h * 4 + r];
            wr[0] = a.x; wr[1] = a.y; wr[2] = a.z; wr[3] = a.w;
            wr[4] = b.x; wr[5] = b.y; wr[6] = b.z; wr[7] = b.w;
            wr[8] = c.x; wr[9] = c.y; wr[10] = c.z; wr[11] = c.w;
            wr[12] = d.x; wr[13] = d.y; wr[14] = d.z; wr[15] = d.w;
        }
    }

    for (int i = wid; i < n; i += total_waves) {
        const float4* xp = (const float4*)(x + (size_t)i * F0);
        float4 xa = xp[lane];
        float4 xb = xp[64 + lane];
        float acc[16];
#pragma unroll
        for (int j = 0; j < 16; j++) {
            acc[j] = xa.x * w[0][j] + xa.y * w[1][j] + xa.z * w[2][j] + xa.w * w[3][j]
                   + xb.x * w[4][j] + xb.y * w[5][j] + xb.z * w[6][j] + xb.w * w[7][j];
        }
#pragma unroll
        for (int j = 0; j < 16; j++) {
            float v = acc[j];
            v += __shfl_xor(v, 1);
            v += __shfl_xor(v, 2);
            v += __shfl_xor(v, 4);
            v += __shfl_xor(v, 8);
            v += __shfl_xor(v, 16);
            v += __shfl_xor(v, 32);
            acc[j] = v;
        }
        if (lane < 16) {
            float v = acc[0];
#pragma unroll
            for (int j = 1; j < 16; j++) v = (lane == j) ? acc[j] : v;
            hp[(size_t)i * F1 + lane] = dinv[i] * v;
        }
    }
}

// ---------------- SpMM1 + relu, store s2 = dinv * h1 (16 feats) ----------------
__global__ __launch_bounds__(256) void k_spmm1(const float* __restrict__ hp,
                                               const int* __restrict__ rs,
                                               const int* __restrict__ deg,
                                               const int* __restrict__ colsort,
                                               const float* __restrict__ dinv,
                                               const float* __restrict__ b1,
                                               float* __restrict__ s2, int n) {
    int t = threadIdx.x;
    int lane = t & 63;
    int g = lane >> 4;
    int jf = lane & 15;
    int i = blockIdx.x * 4 + (t >> 6);
    if (i >= n) return;
    int s = rs[i], c = deg[i];
    float acc = (g == 0) ? hp[(size_t)i * F1 + jf] : 0.f;
    int e = g;
    for (; e + 4 < c; e += 8) {
        int c0 = colsort[s + e];
        int c1 = colsort[s + e + 4];
        float v0 = hp[(size_t)c0 * F1 + jf];
        float v1 = hp[(size_t)c1 * F1 + jf];
        acc += v0 + v1;
    }
    if (e < c) acc += hp[(size_t)colsort[s + e] * F1 + jf];
    acc += __shfl_xor(acc, 16);
    acc += __shfl_xor(acc, 32);
    float di = dinv[i];
    float h1 = fmaxf(di * acc + b1[jf], 0.f);
    if (lane < 16) s2[(size_t)i * F1 + jf] = di * h1;
}

// ---------------- SpMM2 (16 feats) + GEMM2 + bias + log_softmax ----------------
__global__ __launch_bounds__(256) void k_spmm2(const float* __restrict__ s2,
                                               const int* __restrict__ rs,
                                               const int* __restrict__ deg,
                                               const int* __restrict__ colsort,
                                               const float* __restrict__ dinv,
                                               const float* __restrict__ W2,
                                               const float* __restrict__ b2,
                                               float* __restrict__ out, int n) {
    __shared__ float sW2[F1 * F2];
    int t = threadIdx.x;
    for (int idx = t; idx < F1 * F2; idx += 256) sW2[idx] = W2[idx];
    __syncthreads();

    int lane = t & 63;
    int g = lane >> 4;
    int jf = lane & 15;
    int i = blockIdx.x * 4 + (t >> 6);
    if (i >= n) return;
    int s = rs[i], c = deg[i];
    float acc = (g == 0) ? s2[(size_t)i * F1 + jf] : 0.f;
    int e = g;
    for (; e + 4 < c; e += 8) {
        int c0 = colsort[s + e];
        int c1 = colsort[s + e + 4];
        float v0 = s2[(size_t)c0 * F1 + jf];
        float v1 = s2[(size_t)c1 * F1 + jf];
        acc += v0 + v1;
    }
    if (e < c) acc += s2[(size_t)colsort[s + e] * F1 + jf];
    acc += __shfl_xor(acc, 16);
    acc += __shfl_xor(acc, 32);
    float z = dinv[i] * acc;

    bool act = lane < F2;
    int k = act ? lane : 0;
    float o = 0.f;
#pragma unroll
    for (int j = 0; j < F1; j++) {
        float zj = __shfl(z, j);
        o += zj * sW2[j * F2 + k];
    }
    float val = act ? o + b2[k] : -INFINITY;
    float m = val;
#pragma unroll
    for (int off = 1; off < 64; off <<= 1) m = fmaxf(m, __shfl_xor(m, off));
    float ex = act ? __expf(val - m) : 0.f;
    float ssum = ex;
#pragma unroll
    for (int off = 1; off < 64; off <<= 1) ssum += __shfl_xor(ssum, off);
    if (act) out[(size_t)i * F2 + lane] = val - m - __logf(ssum);
}

extern "C" void kernel_launch(void* const* d_in, const int* in_sizes, int n_in,
                              void* d_out, int out_size, void* d_ws, size_t ws_size,
                              hipStream_t stream) {
    const float* x  = (const float*)d_in[0];
    const float* W1 = (const float*)d_in[1];
    const float* b1 = (const float*)d_in[2];
    const float* W2 = (const float*)d_in[3];
    const float* b2 = (const float*)d_in[4];
    const int*   ei = (const int*)d_in[5];

    int n = in_sizes[0] / F0;
    int E = in_sizes[5] / 2;
    const int* row = ei;
    const int* col = ei + E;
    int NB = (n + RPB - 1) >> RPB_SHIFT;
    int NEL = NB << NG_SHIFT;

    // workspace carve-up (4-byte elements)
    int* deg     = (int*)d_ws;          // n
    int* rs      = deg + n;             // n
    float* dinv  = (float*)(rs + n);    // n
    int* bhist   = (int*)(dinv + n);    // NB*NG
    int* bcursor = bhist + NEL;         // NB*NG
    int* bstart  = bcursor + NEL;       // NB
    int* colsort = bstart + NB;         // E
    int* ebuf    = colsort + E;         // max(E, 32n) — overlaid with hp/s2 below
    float* hp    = (float*)ebuf;        // n x 16 (ebuf dead after k_bsort)
    float* s2    = hp + (size_t)n * F1; // n x 16

    k_zero<<<(NEL + 255) / 256, 256, 0, stream>>>(bhist, NEL);
    k_bhist<<<(E + 1023) / 1024, 256, 0, stream>>>(row, E, bhist);
    k_bscan<<<1, 1024, 0, stream>>>(bhist, NEL, bcursor, bstart);
    k_bfill<<<(E + 1023) / 1024, 256, 0, stream>>>(row, col, E, bcursor, ebuf);
    k_bsort<<<NB, 256, 0, stream>>>(ebuf, bstart, NB, E, n, colsort, deg, rs, dinv);

    int g1_blocks = 2048;
    k_gemm1<<<g1_blocks, 256, 0, stream>>>(x, W1, dinv, hp, n, g1_blocks * 4);
    k_spmm1<<<(n + 3) / 4, 256, 0, stream>>>(hp, rs, deg, colsort, dinv, b1, s2, n);
    k_spmm2<<<(n + 3) / 4, 256, 0, stream>>>(s2, rs, deg, colsort, dinv, W2, b2,
                                             (float*)d_out, n);
}